// Round 8
// baseline (49.808 us; speedup 1.0000x reference)
//
#include <hip/hip_runtime.h>

#define B_ 16
#define U_ 500
#define S_ 256
#define H_ 128
#define UTILE 32
#define NWAVES 16
#define TPB (NWAVES * 64)
#define HHALF 64

// R0 structure, but E is staged in two 64-h passes through a half-size buffer:
// LDS 154K -> ~80K  =>  2 blocks/CU (8 waves/SIMD), zero duplicated work.
__global__ __launch_bounds__(TPB, 8) void attn_kernel(
    const float* __restrict__ user,     // (B,U,4)
    const float* __restrict__ server,   // (B,S,6)
    const int*   __restrict__ masks,    // (B,U,S) int32 0/1 OR packed bytes (auto-detected)
    const float* __restrict__ Wu,       // (3,H)
    const float* __restrict__ bu,       // (H)
    const float* __restrict__ Ws,       // (7,H)  (row 6 multiplies the zero 'active' col -> unused)
    const float* __restrict__ bs,       // (H)
    const float* __restrict__ W1,       // (H,H)
    const float* __restrict__ W2,       // (H,H)
    const float* __restrict__ vt,       // (H)
    float* __restrict__ out)            // (B,U,S) fp32
{
  __shared__ float E[HHALF][S_];        // 64 KB, [h_local][s], exp(2*enc) for current h-half
  __shared__ float M1s[6 * H_];         // 2*(Ws@W1) rows 0..5 (pre-doubled)
  __shared__ float M2s[3 * H_];         // 2*(Wu@W2)
  __shared__ float c1s[H_];             // 2*(bs@W1)
  __shared__ float c2s[H_];             // 2*(bu@W2)
  __shared__ float vts[H_];             // vt (NOT doubled)
  __shared__ float decs[NWAVES][2][HHALF]; // exp(2*dec) for current h-half, 8 KB
  __shared__ float vsum_s;

  const int tid = threadIdx.x;
  const int bid = blockIdx.x;
  const int b   = bid >> 4;
  const int u0  = (bid & 15) * UTILE;

  // ---- phase 0: fused weight products, PRE-DOUBLED (folds the 2x inside exp) ----
  {
    const int h = tid & (H_ - 1);
    for (int job = tid >> 7; job < 11; job += 8) {
      const float* Lv; const float* Rm; float* dst;
      if (job < 6)       { Lv = Ws + job * H_;       Rm = W1; dst = M1s + job * H_; }
      else if (job == 6) { Lv = bs;                  Rm = W1; dst = c1s; }
      else if (job < 10) { Lv = Wu + (job - 7) * H_; Rm = W2; dst = M2s + (job - 7) * H_; }
      else               { Lv = bu;                  Rm = W2; dst = c2s; }
      float acc = 0.f;
      for (int j = 0; j < H_; ++j) acc = fmaf(Lv[j], Rm[j * H_ + h], acc);
      dst[h] = acc + acc;               // pre-doubled
    }
    if (tid < H_) vts[tid] = vt[tid];
    if (tid < 64) {                     // vsum = sum(vt), from global (no LDS dep)
      float v = vt[tid] + vt[tid + 64];
      #pragma unroll
      for (int off = 32; off > 0; off >>= 1) v += __shfl_xor(v, off, 64);
      if (tid == 0) vsum_s = v;
    }
  }

  // ---- mask dtype detection: int32 masks are strictly 0/1; packed bytes make words >1 ----
  int lflag;
  {
    int4 mw = *reinterpret_cast<const int4*>(masks + tid * 4);   // first 16 KB, in-bounds either way
    lflag = ((unsigned)mw.x > 1u) | ((unsigned)mw.y > 1u) |
            ((unsigned)mw.z > 1u) | ((unsigned)mw.w > 1u);
  }
  const int bytemode = __syncthreads_or(lflag);   // barrier also publishes phase-0 LDS

  const int w    = tid >> 6;
  const int lane = tid & 63;
  const int uA   = u0 + 2 * w;          // pairs both-valid or both-invalid (U_ even, u0 even)
  const int uAc  = min(uA,     U_ - 1);
  const int uBc  = min(uA + 1, U_ - 1);

  // user features for both rows, held in regs across both passes
  const float* uvA = user + ((size_t)b * U_ + uAc) * 4;
  const float* uvB = user + ((size_t)b * U_ + uBc) * 4;
  const float gA0 = uvA[0], gA1 = uvA[1], gA2 = uvA[2];
  const float gB0 = uvB[0], gB1 = uvB[1], gB2 = uvB[2];

  // server features for this thread's staging column, held in regs across passes
  const int sStage = tid & (S_ - 1);
  const int h0     = tid >> 8;          // 0..3, wave-uniform
  const float2* sv = reinterpret_cast<const float2*>(server + ((size_t)b * S_ + sStage) * 6);
  const float2 p0 = sv[0], p1 = sv[1], p2 = sv[2];

  // ---- issue mask loads early; HBM latency hides under pass-0 staging ----
  const size_t ridxA = ((size_t)b * U_ + uAc) * S_ + (size_t)lane * 4;
  const size_t ridxB = ((size_t)b * U_ + uBc) * S_ + (size_t)lane * 4;
  int mA0, mA1, mA2, mA3, mB0, mB1, mB2, mB3;
  if (!bytemode) {
    int4 mm = *reinterpret_cast<const int4*>(masks + ridxA);
    mA0 = mm.x; mA1 = mm.y; mA2 = mm.z; mA3 = mm.w;
    int4 nn = *reinterpret_cast<const int4*>(masks + ridxB);
    mB0 = nn.x; mB1 = nn.y; mB2 = nn.z; mB3 = nn.w;
  } else {
    const unsigned char* mb = reinterpret_cast<const unsigned char*>(masks);
    uchar4 mm = *reinterpret_cast<const uchar4*>(mb + ridxA);
    mA0 = mm.x; mA1 = mm.y; mA2 = mm.z; mA3 = mm.w;
    uchar4 nn = *reinterpret_cast<const uchar4*>(mb + ridxB);
    mB0 = nn.x; mB1 = nn.y; mB2 = nn.z; mB3 = nn.w;
  }

  float aA0 = 0.f, aA1 = 0.f, aA2 = 0.f, aA3 = 0.f;
  float aB0 = 0.f, aB1 = 0.f, aB2 = 0.f, aB3 = 0.f;

  #pragma unroll 1
  for (int pass = 0; pass < 2; ++pass) {
    const int hbase = pass * HHALF;
    if (pass) __syncthreads();          // all reads of E done before overwrite

    // ---- stage E[hr][s] = exp(2*enc) for h = hbase+hr (weights pre-doubled) ----
    for (int hr = h0; hr < HHALF; hr += 4) {
      const int h = hbase + hr;
      float a = c1s[h];
      a = fmaf(p0.x, M1s[0 * H_ + h], a);
      a = fmaf(p0.y, M1s[1 * H_ + h], a);
      a = fmaf(p1.x, M1s[2 * H_ + h], a);
      a = fmaf(p1.y, M1s[3 * H_ + h], a);
      a = fmaf(p2.x, M1s[4 * H_ + h], a);
      a = fmaf(p2.y, M1s[5 * H_ + h], a);
      E[hr][sStage] = __expf(fminf(fmaxf(a, -60.f), 60.f));
    }
    // ---- stage dec rows for this h-half: lane covers h = hbase+lane ----
    {
      const int h = hbase + lane;
      float a0 = c2s[h];
      a0 = fmaf(gA0, M2s[0 * H_ + h], a0);
      a0 = fmaf(gA1, M2s[1 * H_ + h], a0);
      a0 = fmaf(gA2, M2s[2 * H_ + h], a0);
      decs[w][0][lane] = __expf(fminf(fmaxf(a0, -60.f), 60.f));
      float a1 = c2s[h];
      a1 = fmaf(gB0, M2s[0 * H_ + h], a1);
      a1 = fmaf(gB1, M2s[1 * H_ + h], a1);
      a1 = fmaf(gB2, M2s[2 * H_ + h], a1);
      decs[w][1][lane] = __expf(fminf(fmaxf(a1, -60.f), 60.f));
    }
    __syncthreads();                    // publish E + decs

    // ---- accumulate this h-half: lane owns s = 4l..4l+3 for both u-rows ----
    #pragma unroll 4
    for (int h4 = 0; h4 < HHALF / 4; ++h4) {
      const float4 e0 = *reinterpret_cast<const float4*>(&E[h4 * 4 + 0][lane * 4]);
      const float4 e1 = *reinterpret_cast<const float4*>(&E[h4 * 4 + 1][lane * 4]);
      const float4 e2 = *reinterpret_cast<const float4*>(&E[h4 * 4 + 2][lane * 4]);
      const float4 e3 = *reinterpret_cast<const float4*>(&E[h4 * 4 + 3][lane * 4]);
      const float4 dA = *reinterpret_cast<const float4*>(&decs[w][0][h4 * 4]);   // LDS broadcast
      const float4 dB = *reinterpret_cast<const float4*>(&decs[w][1][h4 * 4]);   // LDS broadcast
      const float4 v4 = *reinterpret_cast<const float4*>(&vts[hbase + h4 * 4]);  // LDS broadcast

      auto quad = [&v4](float ea, float eb, float ec, float ed, const float4& d, float& acc) {
        float t0 = fmaf(ea, d.x, 1.0f);
        float t1 = fmaf(eb, d.y, 1.0f);
        float t2 = fmaf(ec, d.z, 1.0f);
        float t3 = fmaf(ed, d.w, 1.0f);
        float t01 = t0 * t1;
        float t23 = t2 * t3;
        float n01 = fmaf(v4.x, t1, v4.y * t0);
        float n23 = fmaf(v4.z, t3, v4.w * t2);
        float den = t01 * t23;
        float num = fmaf(n01, t23, n23 * t01);
        acc = fmaf(num, __builtin_amdgcn_rcpf(den), acc);
      };
      quad(e0.x, e1.x, e2.x, e3.x, dA, aA0);
      quad(e0.y, e1.y, e2.y, e3.y, dA, aA1);
      quad(e0.z, e1.z, e2.z, e3.z, dA, aA2);
      quad(e0.w, e1.w, e2.w, e3.w, dA, aA3);
      quad(e0.x, e1.x, e2.x, e3.x, dB, aB0);
      quad(e0.y, e1.y, e2.y, e3.y, dB, aB1);
      quad(e0.z, e1.z, e2.z, e3.z, dB, aB2);
      quad(e0.w, e1.w, e2.w, e3.w, dB, aB3);
    }
  }

  // ---- mask + softmax + store (wave-uniform validity: both rows valid or both invalid) ----
  if (uA < U_) {
    const float negs = -103.6163291847321f * 10.0f;   // log(1e-45) * EXPLORATION_C
    const float vs10 = vsum_s * 10.0f;
    #pragma unroll
    for (int r = 0; r < 2; ++r) {
      const float b0 = r ? aB0 : aA0, b1 = r ? aB1 : aA1;
      const float b2 = r ? aB2 : aA2, b3 = r ? aB3 : aA3;
      const int   m0 = r ? mB0 : mA0, m1 = r ? mB1 : mA1;
      const int   m2 = r ? mB2 : mA2, m3 = r ? mB3 : mA3;
      float s0 = m0 ? fmaf(-20.0f, b0, vs10) : negs;
      float s1 = m1 ? fmaf(-20.0f, b1, vs10) : negs;
      float s2 = m2 ? fmaf(-20.0f, b2, vs10) : negs;
      float s3 = m3 ? fmaf(-20.0f, b3, vs10) : negs;
      float mx = fmaxf(fmaxf(s0, s1), fmaxf(s2, s3));
      #pragma unroll
      for (int off = 32; off > 0; off >>= 1) mx = fmaxf(mx, __shfl_xor(mx, off, 64));
      float p0_ = __expf(s0 - mx);
      float p1_ = __expf(s1 - mx);
      float p2_ = __expf(s2 - mx);
      float p3_ = __expf(s3 - mx);
      float sum = (p0_ + p1_) + (p2_ + p3_);
      #pragma unroll
      for (int off = 32; off > 0; off >>= 1) sum += __shfl_xor(sum, off, 64);
      const float inv = __builtin_amdgcn_rcpf(sum);
      float4 o;
      o.x = p0_ * inv; o.y = p1_ * inv; o.z = p2_ * inv; o.w = p3_ * inv;
      *reinterpret_cast<float4*>(out + (r ? ridxB : ridxA)) = o;
    }
  }
}

extern "C" void kernel_launch(void* const* d_in, const int* in_sizes, int n_in,
                              void* d_out, int out_size, void* d_ws, size_t ws_size,
                              hipStream_t stream) {
  const float* user   = (const float*)d_in[0];
  const float* server = (const float*)d_in[1];
  const int*   masks  = (const int*)d_in[2];
  const float* Wu = (const float*)d_in[3];
  const float* bu = (const float*)d_in[4];
  const float* Ws = (const float*)d_in[5];
  const float* bs = (const float*)d_in[6];
  const float* W1 = (const float*)d_in[7];
  const float* W2 = (const float*)d_in[8];
  const float* vt = (const float*)d_in[9];
  float* out = (float*)d_out;
  (void)in_sizes; (void)n_in; (void)out_size; (void)d_ws; (void)ws_size;

  attn_kernel<<<dim3(B_ * ((U_ + UTILE - 1) / UTILE)), dim3(TPB), 0, stream>>>(
      user, server, masks, Wu, bu, Ws, bs, W1, W2, vt, out);
}

// Round 9
// 45.603 us; speedup vs baseline: 1.0922x; 1.0922x over previous
//
#include <hip/hip_runtime.h>

#define B_ 16
#define U_ 500
#define S_ 256
#define H_ 128
#define UTILE 32
#define NWAVES 16
#define TPB (NWAVES * 64)
#define HHALF 64
#define SENT 1e30f

// ---------------- Kernel A: partial accumulation, one h-half per block ----------------
// 512 blocks = 2/CU (LDS ~75 KB). Zero duplicated staging: each block does phase-0,
// E-staging, decs ONLY for its 64-h half. half0 writes raw partials to out;
// half1 applies the mask as a +1e30 sentinel and writes partials to ws.
__global__ __launch_bounds__(TPB, 8) void attn_partial(
    const float* __restrict__ user, const float* __restrict__ server,
    const int* __restrict__ masks,
    const float* __restrict__ Wu, const float* __restrict__ bu,
    const float* __restrict__ Ws, const float* __restrict__ bs,
    const float* __restrict__ W1, const float* __restrict__ W2,
    const float* __restrict__ vt,
    float* __restrict__ out, float* __restrict__ ws)
{
  __shared__ float E[HHALF][S_];          // 64 KB
  __shared__ float M1h[6 * HHALF];        // 2*(Ws@W1)[:, half]
  __shared__ float M2h[3 * HHALF];        // 2*(Wu@W2)[:, half]
  __shared__ float c1h[HHALF];
  __shared__ float c2h[HHALF];
  __shared__ float decs[NWAVES][2][HHALF]; // 8 KB

  const int tid   = threadIdx.x;
  const int bid   = blockIdx.x;
  const int pr    = bid >> 1;
  const int hh    = bid & 1;
  const int hbase = hh * HHALF;
  const int b     = pr >> 4;
  const int u0    = (pr & 15) * UTILE;

  // mask dtype probe (first 16 KB — in-bounds for int32 and byte layouts)
  int4 mw = *reinterpret_cast<const int4*>(masks + tid * 4);

  // ---- phase 0: fused weights for THIS half only, pre-doubled ----
  {
    const int hl = tid & (HHALF - 1);
    const int g  = tid >> 6;              // 16 groups of 64; 11 jobs
    if (g < 11) {
      const float* Lv; const float* Rm; float* dst;
      if (g < 6)       { Lv = Ws + g * H_;       Rm = W1; dst = M1h + g * HHALF; }
      else if (g == 6) { Lv = bs;                Rm = W1; dst = c1h; }
      else if (g < 10) { Lv = Wu + (g - 7) * H_; Rm = W2; dst = M2h + (g - 7) * HHALF; }
      else             { Lv = bu;                Rm = W2; dst = c2h; }
      const int h = hbase + hl;
      float acc = 0.f;
      for (int j = 0; j < H_; ++j) acc = fmaf(Lv[j], Rm[j * H_ + h], acc);
      dst[hl] = acc + acc;                // pre-doubled (folds 2x inside exp)
    }
  }
  const int lflag = ((unsigned)mw.x > 1u) | ((unsigned)mw.y > 1u) |
                    ((unsigned)mw.z > 1u) | ((unsigned)mw.w > 1u);
  const int bytemode = __syncthreads_or(lflag);   // publishes phase-0 LDS too

  // ---- stage E[hr][s] for this half ----
  {
    const int s  = tid & (S_ - 1);
    const int h0 = tid >> 8;              // 0..3
    const float2* sv = reinterpret_cast<const float2*>(server + ((size_t)b * S_ + s) * 6);
    const float2 p0 = sv[0], p1 = sv[1], p2 = sv[2];
    for (int hr = h0; hr < HHALF; hr += 4) {
      float a = c1h[hr];
      a = fmaf(p0.x, M1h[0 * HHALF + hr], a);
      a = fmaf(p0.y, M1h[1 * HHALF + hr], a);
      a = fmaf(p1.x, M1h[2 * HHALF + hr], a);
      a = fmaf(p1.y, M1h[3 * HHALF + hr], a);
      a = fmaf(p2.x, M1h[4 * HHALF + hr], a);
      a = fmaf(p2.y, M1h[5 * HHALF + hr], a);
      E[hr][s] = __expf(fminf(fmaxf(a, -60.f), 60.f));
    }
  }

  const int w    = tid >> 6;
  const int lane = tid & 63;
  const int uA   = u0 + 2 * w;            // both-valid or both-invalid (U_ even)
  const int uAc  = min(uA,     U_ - 1);
  const int uBc  = min(uA + 1, U_ - 1);

  // ---- decs for this half (lane covers the 64 local h) ----
  {
    const float* uvA = user + ((size_t)b * U_ + uAc) * 4;
    const float* uvB = user + ((size_t)b * U_ + uBc) * 4;
    const float gA0 = uvA[0], gA1 = uvA[1], gA2 = uvA[2];
    const float gB0 = uvB[0], gB1 = uvB[1], gB2 = uvB[2];
    float a0 = c2h[lane];
    a0 = fmaf(gA0, M2h[0 * HHALF + lane], a0);
    a0 = fmaf(gA1, M2h[1 * HHALF + lane], a0);
    a0 = fmaf(gA2, M2h[2 * HHALF + lane], a0);
    decs[w][0][lane] = __expf(fminf(fmaxf(a0, -60.f), 60.f));
    float a1 = c2h[lane];
    a1 = fmaf(gB0, M2h[0 * HHALF + lane], a1);
    a1 = fmaf(gB1, M2h[1 * HHALF + lane], a1);
    a1 = fmaf(gB2, M2h[2 * HHALF + lane], a1);
    decs[w][1][lane] = __expf(fminf(fmaxf(a1, -60.f), 60.f));
  }
  __syncthreads();

  // ---- main accumulation over this half: lane owns s=4l..4l+3 for both u-rows ----
  float aA0 = 0.f, aA1 = 0.f, aA2 = 0.f, aA3 = 0.f;
  float aB0 = 0.f, aB1 = 0.f, aB2 = 0.f, aB3 = 0.f;
  #pragma unroll 4
  for (int h4 = 0; h4 < HHALF / 4; ++h4) {
    const float4 e0 = *reinterpret_cast<const float4*>(&E[h4 * 4 + 0][lane * 4]);
    const float4 e1 = *reinterpret_cast<const float4*>(&E[h4 * 4 + 1][lane * 4]);
    const float4 e2 = *reinterpret_cast<const float4*>(&E[h4 * 4 + 2][lane * 4]);
    const float4 e3 = *reinterpret_cast<const float4*>(&E[h4 * 4 + 3][lane * 4]);
    const float4 dA = *reinterpret_cast<const float4*>(&decs[w][0][h4 * 4]);  // LDS broadcast
    const float4 dB = *reinterpret_cast<const float4*>(&decs[w][1][h4 * 4]);  // LDS broadcast
    const float4 v4 = *reinterpret_cast<const float4*>(vt + hbase + h4 * 4);  // uniform -> scalar

    auto quad = [&v4](float ea, float eb, float ec, float ed, const float4& d, float& acc) {
      float t0 = fmaf(ea, d.x, 1.0f);
      float t1 = fmaf(eb, d.y, 1.0f);
      float t2 = fmaf(ec, d.z, 1.0f);
      float t3 = fmaf(ed, d.w, 1.0f);
      float t01 = t0 * t1;
      float t23 = t2 * t3;
      float n01 = fmaf(v4.x, t1, v4.y * t0);
      float n23 = fmaf(v4.z, t3, v4.w * t2);
      acc = fmaf(fmaf(n01, t23, n23 * t01), __builtin_amdgcn_rcpf(t01 * t23), acc);
    };
    quad(e0.x, e1.x, e2.x, e3.x, dA, aA0);
    quad(e0.y, e1.y, e2.y, e3.y, dA, aA1);
    quad(e0.z, e1.z, e2.z, e3.z, dA, aA2);
    quad(e0.w, e1.w, e2.w, e3.w, dA, aA3);
    quad(e0.x, e1.x, e2.x, e3.x, dB, aB0);
    quad(e0.y, e1.y, e2.y, e3.y, dB, aB1);
    quad(e0.z, e1.z, e2.z, e3.z, dB, aB2);
    quad(e0.w, e1.w, e2.w, e3.w, dB, aB3);
  }

  if (uA >= U_) return;
  const size_t ridxA = ((size_t)b * U_ + uAc) * S_ + (size_t)lane * 4;
  const size_t ridxB = ((size_t)b * U_ + uBc) * S_ + (size_t)lane * 4;

  if (!hh) {                               // half0: raw partials -> out
    float4 o;
    o.x = aA0; o.y = aA1; o.z = aA2; o.w = aA3;
    *reinterpret_cast<float4*>(out + ridxA) = o;
    o.x = aB0; o.y = aB1; o.z = aB2; o.w = aB3;
    *reinterpret_cast<float4*>(out + ridxB) = o;
  } else {                                 // half1: masked-sentinel partials -> ws
    int mA0, mA1, mA2, mA3, mB0, mB1, mB2, mB3;
    if (!bytemode) {
      int4 mm = *reinterpret_cast<const int4*>(masks + ridxA);
      mA0 = mm.x; mA1 = mm.y; mA2 = mm.z; mA3 = mm.w;
      int4 nn = *reinterpret_cast<const int4*>(masks + ridxB);
      mB0 = nn.x; mB1 = nn.y; mB2 = nn.z; mB3 = nn.w;
    } else {
      const unsigned char* mb = reinterpret_cast<const unsigned char*>(masks);
      uchar4 mm = *reinterpret_cast<const uchar4*>(mb + ridxA);
      mA0 = mm.x; mA1 = mm.y; mA2 = mm.z; mA3 = mm.w;
      uchar4 nn = *reinterpret_cast<const uchar4*>(mb + ridxB);
      mB0 = nn.x; mB1 = nn.y; mB2 = nn.z; mB3 = nn.w;
    }
    float4 o;
    o.x = mA0 ? aA0 : SENT; o.y = mA1 ? aA1 : SENT;
    o.z = mA2 ? aA2 : SENT; o.w = mA3 ? aA3 : SENT;
    *reinterpret_cast<float4*>(ws + ridxA) = o;
    o.x = mB0 ? aB0 : SENT; o.y = mB1 ? aB1 : SENT;
    o.z = mB2 ? aB2 : SENT; o.w = mB3 ? aB3 : SENT;
    *reinterpret_cast<float4*>(ws + ridxB) = o;
  }
}

// ---------------- Kernel B: combine halves + softmax (pure streaming) ----------------
// score = vs10 - 20*(p0+p1); masked entries carry p1=1e30 -> score ~ -2e31 -> exp -> 0
// (all-masked rows become uniform 1/256, matching the reference's NEG_FILL softmax).
__global__ __launch_bounds__(TPB) void attn_finish(
    const float* __restrict__ vt, float* __restrict__ out, const float* __restrict__ ws)
{
  const int tid  = threadIdx.x;
  const int bid  = blockIdx.x;
  const int w    = tid >> 6;
  const int lane = tid & 63;
  const int b    = bid >> 5;
  const int u    = (bid & 31) * 16 + w;
  if (u >= U_) return;

  float v = vt[lane] + vt[lane + 64];
  #pragma unroll
  for (int off = 32; off > 0; off >>= 1) v += __shfl_xor(v, off, 64);
  const float vs10 = v * 10.0f;

  const size_t row = ((size_t)b * U_ + u) * S_ + (size_t)lane * 4;
  const float4 P0 = *reinterpret_cast<const float4*>(out + row);
  const float4 P1 = *reinterpret_cast<const float4*>(ws + row);
  float s0 = fmaf(-20.0f, P0.x + P1.x, vs10);
  float s1 = fmaf(-20.0f, P0.y + P1.y, vs10);
  float s2 = fmaf(-20.0f, P0.z + P1.z, vs10);
  float s3 = fmaf(-20.0f, P0.w + P1.w, vs10);
  float mx = fmaxf(fmaxf(s0, s1), fmaxf(s2, s3));
  #pragma unroll
  for (int off = 32; off > 0; off >>= 1) mx = fmaxf(mx, __shfl_xor(mx, off, 64));
  float p0 = __expf(s0 - mx);
  float p1 = __expf(s1 - mx);
  float p2 = __expf(s2 - mx);
  float p3 = __expf(s3 - mx);
  float sum = (p0 + p1) + (p2 + p3);
  #pragma unroll
  for (int off = 32; off > 0; off >>= 1) sum += __shfl_xor(sum, off, 64);
  const float inv = __builtin_amdgcn_rcpf(sum);
  float4 o;
  o.x = p0 * inv; o.y = p1 * inv; o.z = p2 * inv; o.w = p3 * inv;
  *reinterpret_cast<float4*>(out + row) = o;
}

// ---------------- Fallback: proven R0 monolithic kernel (44.4 us) ----------------
__global__ __launch_bounds__(TPB, 1) void attn_mono(
    const float* __restrict__ user, const float* __restrict__ server,
    const int* __restrict__ masks,
    const float* __restrict__ Wu, const float* __restrict__ bu,
    const float* __restrict__ Ws, const float* __restrict__ bs,
    const float* __restrict__ W1, const float* __restrict__ W2,
    const float* __restrict__ vt, float* __restrict__ out)
{
  __shared__ float E[H_][S_];
  __shared__ float M1s[6 * H_];
  __shared__ float M2s[3 * H_];
  __shared__ float c1s[H_];
  __shared__ float c2s[H_];
  __shared__ float vts[H_];
  __shared__ float decs[NWAVES][2][H_];
  __shared__ float vsum_s;

  const int tid = threadIdx.x;
  const int bid = blockIdx.x;
  const int b   = bid >> 4;
  const int u0  = (bid & 15) * UTILE;

  {
    const int h = tid & (H_ - 1);
    for (int job = tid >> 7; job < 11; job += 8) {
      const float* Lv; const float* Rm; float* dst;
      if (job < 6)       { Lv = Ws + job * H_;       Rm = W1; dst = M1s + job * H_; }
      else if (job == 6) { Lv = bs;                  Rm = W1; dst = c1s; }
      else if (job < 10) { Lv = Wu + (job - 7) * H_; Rm = W2; dst = M2s + (job - 7) * H_; }
      else               { Lv = bu;                  Rm = W2; dst = c2s; }
      float acc = 0.f;
      for (int j = 0; j < H_; ++j) acc = fmaf(Lv[j], Rm[j * H_ + h], acc);
      dst[h] = acc;
    }
    if (tid < H_) vts[tid] = vt[tid];
    if (tid < 64) {
      float v = vt[tid] + vt[tid + 64];
      #pragma unroll
      for (int off = 32; off > 0; off >>= 1) v += __shfl_xor(v, off, 64);
      if (tid == 0) vsum_s = v;
    }
  }
  int lflag;
  {
    int4 mw = *reinterpret_cast<const int4*>(masks + tid * 4);
    lflag = ((unsigned)mw.x > 1u) | ((unsigned)mw.y > 1u) |
            ((unsigned)mw.z > 1u) | ((unsigned)mw.w > 1u);
  }
  const int bytemode = __syncthreads_or(lflag);
  {
    const int s  = tid & (S_ - 1);
    const int h0 = tid >> 8;
    const float2* sv = reinterpret_cast<const float2*>(server + ((size_t)b * S_ + s) * 6);
    const float2 p0 = sv[0], p1 = sv[1], p2 = sv[2];
    for (int h = h0; h < H_; h += 4) {
      float a = c1s[h];
      a = fmaf(p0.x, M1s[0 * H_ + h], a);
      a = fmaf(p0.y, M1s[1 * H_ + h], a);
      a = fmaf(p1.x, M1s[2 * H_ + h], a);
      a = fmaf(p1.y, M1s[3 * H_ + h], a);
      a = fmaf(p2.x, M1s[4 * H_ + h], a);
      a = fmaf(p2.y, M1s[5 * H_ + h], a);
      E[h][s] = __expf(fminf(fmaxf(a + a, -60.f), 60.f));
    }
  }
  const int w    = tid >> 6;
  const int lane = tid & 63;
  const int uA   = u0 + 2 * w;
  const int uAc  = min(uA,     U_ - 1);
  const int uBc  = min(uA + 1, U_ - 1);
  {
    const float* uvA = user + ((size_t)b * U_ + uAc) * 4;
    const float* uvB = user + ((size_t)b * U_ + uBc) * 4;
    const float gA0 = uvA[0], gA1 = uvA[1], gA2 = uvA[2];
    const float gB0 = uvB[0], gB1 = uvB[1], gB2 = uvB[2];
    #pragma unroll
    for (int r = 0; r < 2; ++r) {
      const int h1 = lane, h2 = lane + 64;
      const float g0 = r ? gB0 : gA0, g1 = r ? gB1 : gA1, g2 = r ? gB2 : gA2;
      float a0 = c2s[h1];
      a0 = fmaf(g0, M2s[0 * H_ + h1], a0);
      a0 = fmaf(g1, M2s[1 * H_ + h1], a0);
      a0 = fmaf(g2, M2s[2 * H_ + h1], a0);
      decs[w][r][h1] = __expf(fminf(fmaxf(a0 + a0, -60.f), 60.f));
      float a1 = c2s[h2];
      a1 = fmaf(g0, M2s[0 * H_ + h2], a1);
      a1 = fmaf(g1, M2s[1 * H_ + h2], a1);
      a1 = fmaf(g2, M2s[2 * H_ + h2], a1);
      decs[w][r][h2] = __expf(fminf(fmaxf(a1 + a1, -60.f), 60.f));
    }
  }
  __syncthreads();
  const size_t ridxA = ((size_t)b * U_ + uAc) * S_ + (size_t)lane * 4;
  const size_t ridxB = ((size_t)b * U_ + uBc) * S_ + (size_t)lane * 4;
  int mA0, mA1, mA2, mA3, mB0, mB1, mB2, mB3;
  if (!bytemode) {
    int4 mm = *reinterpret_cast<const int4*>(masks + ridxA);
    mA0 = mm.x; mA1 = mm.y; mA2 = mm.z; mA3 = mm.w;
    int4 nn = *reinterpret_cast<const int4*>(masks + ridxB);
    mB0 = nn.x; mB1 = nn.y; mB2 = nn.z; mB3 = nn.w;
  } else {
    const unsigned char* mb = reinterpret_cast<const unsigned char*>(masks);
    uchar4 mm = *reinterpret_cast<const uchar4*>(mb + ridxA);
    mA0 = mm.x; mA1 = mm.y; mA2 = mm.z; mA3 = mm.w;
    uchar4 nn = *reinterpret_cast<const uchar4*>(mb + ridxB);
    mB0 = nn.x; mB1 = nn.y; mB2 = nn.z; mB3 = nn.w;
  }
  float aA0 = 0.f, aA1 = 0.f, aA2 = 0.f, aA3 = 0.f;
  float aB0 = 0.f, aB1 = 0.f, aB2 = 0.f, aB3 = 0.f;
  #pragma unroll 4
  for (int h4 = 0; h4 < H_ / 4; ++h4) {
    const float4 e0 = *reinterpret_cast<const float4*>(&E[h4 * 4 + 0][lane * 4]);
    const float4 e1 = *reinterpret_cast<const float4*>(&E[h4 * 4 + 1][lane * 4]);
    const float4 e2 = *reinterpret_cast<const float4*>(&E[h4 * 4 + 2][lane * 4]);
    const float4 e3 = *reinterpret_cast<const float4*>(&E[h4 * 4 + 3][lane * 4]);
    const float4 dA = *reinterpret_cast<const float4*>(&decs[w][0][h4 * 4]);
    const float4 dB = *reinterpret_cast<const float4*>(&decs[w][1][h4 * 4]);
    const float4 v4 = *reinterpret_cast<const float4*>(&vts[h4 * 4]);
    auto quad = [&v4](float ea, float eb, float ec, float ed, const float4& d, float& acc) {
      float t0 = fmaf(ea, d.x, 1.0f);
      float t1 = fmaf(eb, d.y, 1.0f);
      float t2 = fmaf(ec, d.z, 1.0f);
      float t3 = fmaf(ed, d.w, 1.0f);
      float t01 = t0 * t1;
      float t23 = t2 * t3;
      float n01 = fmaf(v4.x, t1, v4.y * t0);
      float n23 = fmaf(v4.z, t3, v4.w * t2);
      acc = fmaf(fmaf(n01, t23, n23 * t01), __builtin_amdgcn_rcpf(t01 * t23), acc);
    };
    quad(e0.x, e1.x, e2.x, e3.x, dA, aA0);
    quad(e0.y, e1.y, e2.y, e3.y, dA, aA1);
    quad(e0.z, e1.z, e2.z, e3.z, dA, aA2);
    quad(e0.w, e1.w, e2.w, e3.w, dA, aA3);
    quad(e0.x, e1.x, e2.x, e3.x, dB, aB0);
    quad(e0.y, e1.y, e2.y, e3.y, dB, aB1);
    quad(e0.z, e1.z, e2.z, e3.z, dB, aB2);
    quad(e0.w, e1.w, e2.w, e3.w, dB, aB3);
  }
  if (uA < U_) {
    const float negs = -103.6163291847321f * 10.0f;
    const float vs10 = vsum_s * 10.0f;
    #pragma unroll
    for (int r = 0; r < 2; ++r) {
      const float b0 = r ? aB0 : aA0, b1 = r ? aB1 : aA1;
      const float b2 = r ? aB2 : aA2, b3 = r ? aB3 : aA3;
      const int   m0 = r ? mB0 : mA0, m1 = r ? mB1 : mA1;
      const int   m2 = r ? mB2 : mA2, m3 = r ? mB3 : mA3;
      float s0 = m0 ? fmaf(-20.0f, b0, vs10) : negs;
      float s1 = m1 ? fmaf(-20.0f, b1, vs10) : negs;
      float s2 = m2 ? fmaf(-20.0f, b2, vs10) : negs;
      float s3 = m3 ? fmaf(-20.0f, b3, vs10) : negs;
      float mx = fmaxf(fmaxf(s0, s1), fmaxf(s2, s3));
      #pragma unroll
      for (int off = 32; off > 0; off >>= 1) mx = fmaxf(mx, __shfl_xor(mx, off, 64));
      float p0 = __expf(s0 - mx);
      float p1 = __expf(s1 - mx);
      float p2 = __expf(s2 - mx);
      float p3 = __expf(s3 - mx);
      float sum = (p0 + p1) + (p2 + p3);
      #pragma unroll
      for (int off = 32; off > 0; off >>= 1) sum += __shfl_xor(sum, off, 64);
      const float inv = __builtin_amdgcn_rcpf(sum);
      float4 o;
      o.x = p0 * inv; o.y = p1 * inv; o.z = p2 * inv; o.w = p3 * inv;
      *reinterpret_cast<float4*>(out + (r ? ridxB : ridxA)) = o;
    }
  }
}

extern "C" void kernel_launch(void* const* d_in, const int* in_sizes, int n_in,
                              void* d_out, int out_size, void* d_ws, size_t ws_size,
                              hipStream_t stream) {
  const float* user   = (const float*)d_in[0];
  const float* server = (const float*)d_in[1];
  const int*   masks  = (const int*)d_in[2];
  const float* Wu = (const float*)d_in[3];
  const float* bu = (const float*)d_in[4];
  const float* Ws = (const float*)d_in[5];
  const float* bs = (const float*)d_in[6];
  const float* W1 = (const float*)d_in[7];
  const float* W2 = (const float*)d_in[8];
  const float* vt = (const float*)d_in[9];
  float* out = (float*)d_out;
  (void)in_sizes; (void)n_in; (void)out_size;

  const size_t need = (size_t)B_ * U_ * S_ * sizeof(float);   // 8.19 MB partial buffer
  if (ws_size >= need) {
    float* wsp = (float*)d_ws;
    attn_partial<<<dim3(2 * B_ * 16), dim3(TPB), 0, stream>>>(
        user, server, masks, Wu, bu, Ws, bs, W1, W2, vt, out, wsp);
    attn_finish<<<dim3(B_ * 32), dim3(TPB), 0, stream>>>(vt, out, wsp);
  } else {
    attn_mono<<<dim3(B_ * 16), dim3(TPB), 0, stream>>>(
        user, server, masks, Wu, bu, Ws, bs, W1, W2, vt, out);
  }
}